// Round 1
// baseline (46.302 us; speedup 1.0000x reference)
//
#include <hip/hip_runtime.h>
#include <math.h>

// HarmonicGenerator: closed-form piecewise-linear cumsum, fp64 phase track.
// N=16, C=256, LF=200, SEG=960, Lw=192000, NH=8, SR=48000.

#define NB   16
#define CCH  256
#define LFR  200
#define SEGL 960
#define LW   (LFR * SEGL)   // 192000
#define NHH  8

__device__ inline double wave_sum64(double v) {
    #pragma unroll
    for (int off = 32; off > 0; off >>= 1) v += __shfl_xor(v, off);
    return v;
}

__device__ inline double wave_incl_scan64(double v) {
    int lane = threadIdx.x & 63;
    #pragma unroll
    for (int off = 1; off < 64; off <<= 1) {
        double t = __shfl_up(v, off);
        if (lane >= off) v += t;
    }
    return v;
}

// Kernel A: per (n,l) frame: channel-norm (ddof=1), octave dot -> f0, 8 mag dots.
// One wave per frame; thread handles 4 channels (c = lane + 64k).
__global__ __launch_bounds__(64)
void hg_frames(const float* __restrict__ x,
               const float* __restrict__ mag_w, const float* __restrict__ mag_b,
               const float* __restrict__ cn_scale, const float* __restrict__ cn_shift,
               const float* __restrict__ oct_w, const float* __restrict__ oct_b,
               double* __restrict__ f0_out, float* __restrict__ mag_out) {
    int bid = blockIdx.x;            // n*LFR + l
    int n = bid / LFR, l = bid % LFR;
    int lane = threadIdx.x;

    const float* xb = x + (size_t)n * CCH * LFR + l;
    double xv[4];
    int cs[4];
    #pragma unroll
    for (int k = 0; k < 4; k++) {
        int c = lane + 64 * k;
        cs[k] = c;
        xv[k] = (double)xb[(size_t)c * LFR];
    }

    double s = xv[0] + xv[1] + xv[2] + xv[3];
    s = wave_sum64(s);
    double mu = s * (1.0 / 256.0);

    double d2 = 0.0;
    #pragma unroll
    for (int k = 0; k < 4; k++) { double d = xv[k] - mu; d2 += d * d; }
    d2 = wave_sum64(d2);
    double sigma = sqrt(d2 * (1.0 / 255.0)) + 1e-4;   // unbiased std + EPS
    double inv = 1.0 / sigma;

    double oct = 0.0;
    #pragma unroll
    for (int k = 0; k < 4; k++) {
        int c = cs[k];
        double xn = (xv[k] - mu) * inv * (double)cn_scale[c] + (double)cn_shift[c];
        oct += xn * (double)oct_w[c];
    }
    oct = wave_sum64(oct) + (double)oct_b[0];

    double f0 = 440.0 * exp2(oct);
    f0 = fmin(fmax(f0, 20.0), 16000.0);
    if (lane == 0) f0_out[n * LFR + l] = f0;

    #pragma unroll
    for (int h = 0; h < NHH; h++) {
        double z = 0.0;
        #pragma unroll
        for (int k = 0; k < 4; k++) z += xv[k] * (double)mag_w[h * CCH + cs[k]];
        z = wave_sum64(z) + (double)mag_b[h];
        if (lane == 0)
            mag_out[((size_t)n * NHH + h) * LFR + l] = (float)exp(fmin(z, 6.0));
    }
}

// Kernel B: per n, exclusive prefix of per-region sums.
// T[n][k] = 480*F[0] + sum_{i<k} 480*(F[i]+F[i+1])  (k = 0..199; T[199] = tail start)
__global__ __launch_bounds__(64)
void hg_prefix(const double* __restrict__ f0, double* __restrict__ T) {
    int n = blockIdx.x;
    int lane = threadIdx.x;
    const double* F = f0 + n * LFR;
    double carry = 480.0 * F[0];
    for (int base = 0; base < LFR; base += 64) {
        int k = base + lane;
        double d = 0.0;
        if (k < LFR - 1) d = 480.0 * (F[k] + F[k + 1]);
        double sc = wave_incl_scan64(d);
        if (k < LFR) T[n * LFR + k] = carry + (sc - d);   // exclusive
        carry += __shfl(sc, 63);
    }
}

// Kernel C: per output sample, closed-form phase + 8 harmonics.
// grid: (LW/512, NB), block 256, 2 samples/thread.
__global__ __launch_bounds__(256)
void hg_wave(const double* __restrict__ f0, const double* __restrict__ T,
             const float* __restrict__ mag, float* __restrict__ out) {
    int n = blockIdx.y;
    int j0 = (blockIdx.x * 256 + threadIdx.x) * 2;

    const double* F  = f0 + n * LFR;
    const double* Tn = T  + n * LFR;
    const float*  Mg = mag + (size_t)n * NHH * LFR;

    const double INV_SR = 1.0 / 48000.0;
    float res[2];

    #pragma unroll
    for (int u = 0; u < 2; u++) {
        int j = j0 + u;
        double tb;
        float mg[NHH];
        if (j < 480) {
            // head: src clipped to 0 -> value F[0]
            tb = (double)(j + 1) * F[0] * INV_SR;
            #pragma unroll
            for (int h = 0; h < NHH; h++) mg[h] = Mg[h * LFR + 0];
        } else if (j >= LW - 480) {
            // tail: src clipped to 199 -> value F[199]
            int p = j - (LW - 480);
            tb = (Tn[LFR - 1] + (double)(p + 1) * F[LFR - 1]) * INV_SR;
            #pragma unroll
            for (int h = 0; h < NHH; h++) mg[h] = Mg[h * LFR + (LFR - 1)];
        } else {
            int k = (j - 480) / 960;
            int p = (j - 480) - k * 960;
            double F0k = F[k], dF = F[k + 1] - F0k;
            double pp = (double)(p + 1);
            tb = (Tn[k] + pp * F0k + dF * (pp * pp) * (1.0 / 1920.0)) * INV_SR;
            float w = ((float)p + 0.5f) * (1.0f / 960.0f);
            #pragma unroll
            for (int h = 0; h < NHH; h++) {
                float a = Mg[h * LFR + k], b = Mg[h * LFR + k + 1];
                mg[h] = a + (b - a) * w;
            }
        }
        float sacc = 0.0f;
        #pragma unroll
        for (int h = 0; h < NHH; h++) {
            double th = (double)(h + 1) * tb;
            double fr = th - floor(th);               // fractional cycles, exact to ~1e-12
            sacc += sinf((float)(fr * 6.283185307179586)) * mg[h];
        }
        res[u] = sacc * 0.125f;
    }

    size_t o = (size_t)n * LW + j0;
    *reinterpret_cast<float2*>(out + o) = make_float2(res[0], res[1]);
}

extern "C" void kernel_launch(void* const* d_in, const int* in_sizes, int n_in,
                              void* d_out, int out_size, void* d_ws, size_t ws_size,
                              hipStream_t stream) {
    const float* x        = (const float*)d_in[0];
    const float* mag_w    = (const float*)d_in[1];
    const float* mag_b    = (const float*)d_in[2];
    const float* cn_scale = (const float*)d_in[3];
    const float* cn_shift = (const float*)d_in[4];
    const float* oct_w    = (const float*)d_in[5];
    const float* oct_b    = (const float*)d_in[6];
    float* out = (float*)d_out;

    // ws layout: f0 (NB*LFR f64) | T (NB*LFR f64) | mag (NB*NHH*LFR f32)
    double* f0  = (double*)d_ws;
    double* T   = f0 + NB * LFR;
    float*  mag = (float*)(T + NB * LFR);

    hg_frames<<<dim3(NB * LFR), dim3(64), 0, stream>>>(
        x, mag_w, mag_b, cn_scale, cn_shift, oct_w, oct_b, f0, mag);
    hg_prefix<<<dim3(NB), dim3(64), 0, stream>>>(f0, T);
    hg_wave<<<dim3(LW / 512, NB), dim3(256), 0, stream>>>(f0, T, mag, out);
}

// Round 2
// 37.049 us; speedup vs baseline: 1.2497x; 1.2497x over previous
//
#include <hip/hip_runtime.h>
#include <math.h>

// HarmonicGenerator: closed-form piecewise-linear cumsum.
// Phase base per region in fp64, per-harmonic work in fp32 via
// frac(h*tb) = frac(h*frac(tb)). HW v_fract/v_sin (revolutions input).
// N=16, C=256, LF=200, SEG=960, Lw=192000, NH=8, SR=48000.

#define NB   16
#define CCH  256
#define LFR  200
#define LW   192000
#define NHH  8
#define NKM  201   // virtual regions: head, 199 body, tail

__device__ inline double wave_sum64(double v) {
    #pragma unroll
    for (int off = 32; off > 0; off >>= 1) v += __shfl_xor(v, off);
    return v;
}
__device__ inline float wave_sum32(float v) {
    #pragma unroll
    for (int off = 32; off > 0; off >>= 1) v += __shfl_xor(v, off);
    return v;
}
__device__ inline double wave_incl_scan64(double v) {
    int lane = threadIdx.x & 63;
    #pragma unroll
    for (int off = 1; off < 64; off <<= 1) {
        double t = __shfl_up(v, off);
        if (lane >= off) v += t;
    }
    return v;
}

// Kernel A: per (n,l) frame: channel-norm (ddof=1) -> octave -> f0 (f64),
// 8 mag dots (f32). One wave per frame, 4 channels per lane.
__global__ __launch_bounds__(64)
void hg_frames(const float* __restrict__ x,
               const float* __restrict__ mag_w, const float* __restrict__ mag_b,
               const float* __restrict__ cn_scale, const float* __restrict__ cn_shift,
               const float* __restrict__ oct_w, const float* __restrict__ oct_b,
               double* __restrict__ f0_out, float* __restrict__ mag_out) {
    int bid = blockIdx.x;            // n*LFR + l
    int n = bid / LFR, l = bid % LFR;
    int lane = threadIdx.x;

    const float* xb = x + (size_t)n * CCH * LFR + l;
    float xv[4];
    int cs[4];
    #pragma unroll
    for (int k = 0; k < 4; k++) {
        int c = lane + 64 * k;
        cs[k] = c;
        xv[k] = xb[(size_t)c * LFR];
    }

    double s = (double)xv[0] + (double)xv[1] + (double)xv[2] + (double)xv[3];
    s = wave_sum64(s);
    double mu = s * (1.0 / 256.0);

    double d2 = 0.0;
    #pragma unroll
    for (int k = 0; k < 4; k++) { double d = (double)xv[k] - mu; d2 += d * d; }
    d2 = wave_sum64(d2);
    double sigma = sqrt(d2 * (1.0 / 255.0)) + 1e-4;   // unbiased std + EPS
    double inv = 1.0 / sigma;

    double oct = 0.0;
    #pragma unroll
    for (int k = 0; k < 4; k++) {
        int c = cs[k];
        double xn = ((double)xv[k] - mu) * inv * (double)cn_scale[c] + (double)cn_shift[c];
        oct += xn * (double)oct_w[c];
    }
    oct = wave_sum64(oct) + (double)oct_b[0];

    double f0 = 440.0 * exp2(oct);
    f0 = fmin(fmax(f0, 20.0), 16000.0);
    if (lane == 0) f0_out[n * LFR + l] = f0;

    #pragma unroll
    for (int h = 0; h < NHH; h++) {
        float z = 0.0f;
        #pragma unroll
        for (int k = 0; k < 4; k++) z = fmaf(xv[k], mag_w[h * CCH + cs[k]], z);
        z = wave_sum32(z) + mag_b[h];
        if (lane == 0)
            mag_out[((size_t)n * NHH + h) * LFR + l] = expf(fminf(z, 6.0f));
    }
}

// Kernel B: per n: exclusive prefix of region sums -> per-region tables.
// Region km=0..200; phase(j) = P + S*pp + Q*pp^2, pp = j - 960*km + 481.
// km=0 (head): P = -480*F0/SR, S = F0/SR, Q = 0  -> phase = F0*(j+1)/SR.
// km=1..199 (body k=km-1): P = T[k]/SR, S = F[k]/SR, Q = dF/(1920*SR).
// km=200 (tail): P = T[199]/SR, S = F[199]/SR, Q = 0.
__global__ __launch_bounds__(64)
void hg_tables(const double* __restrict__ f0, const float* __restrict__ mag,
               double* __restrict__ P, double* __restrict__ S, double* __restrict__ Q,
               float* __restrict__ magA, float* __restrict__ magD) {
    int n = blockIdx.x;
    int lane = threadIdx.x;
    const double* F = f0 + n * LFR;
    const double INV = 1.0 / 48000.0;

    // exclusive scan of region sums 480*(F[k]+F[k+1]); write P[km=k+1]
    double carry = 480.0 * F[0];
    for (int base = 0; base < LFR; base += 64) {
        int k = base + lane;
        double d = (k < LFR - 1) ? 480.0 * (F[k] + F[k + 1]) : 0.0;
        double sc = wave_incl_scan64(d);
        if (k < LFR) P[n * NKM + k + 1] = (carry + sc - d) * INV;
        carry += __shfl(sc, 63);
    }
    if (lane == 0) P[n * NKM] = -480.0 * F[0] * INV;

    for (int km = lane; km < NKM; km += 64) {
        int kc = km - 1;
        if (kc < 0) kc = 0;
        if (kc > LFR - 1) kc = LFR - 1;
        bool body = (km >= 1 && km <= LFR - 1);
        S[n * NKM + km] = F[kc] * INV;
        Q[n * NKM + km] = body ? (F[km] - F[km - 1]) * (INV / 1920.0) : 0.0;
        #pragma unroll
        for (int h = 0; h < NHH; h++) {
            float a = mag[((size_t)n * NHH + h) * LFR + kc];
            float dd = body ? (mag[((size_t)n * NHH + h) * LFR + km] - a) : 0.0f;
            magA[(((size_t)n * NKM) + km) * 8 + h] = a;
            magD[(((size_t)n * NKM) + km) * 8 + h] = dd;
        }
    }
}

// Kernel C: one block per (region, n). All frame params block-uniform.
// grid (201, 16), block 256; <=960 samples per block, strided by 256.
__global__ __launch_bounds__(256)
void hg_wave(const double* __restrict__ P, const double* __restrict__ S,
             const double* __restrict__ Q, const float* __restrict__ magA,
             const float* __restrict__ magD, float* __restrict__ out) {
    int km = blockIdx.x, n = blockIdx.y;
    int tid = threadIdx.x;
    int idx = n * NKM + km;

    double Pv = P[idx], Sv = S[idx], Qv = Q[idx];
    const float4* pa = (const float4*)(magA + (size_t)idx * 8);
    const float4* pd = (const float4*)(magD + (size_t)idx * 8);
    float4 a0 = pa[0], a1 = pa[1], d0 = pd[0], d1 = pd[1];
    float ma[8] = {a0.x, a0.y, a0.z, a0.w, a1.x, a1.y, a1.z, a1.w};
    float md[8] = {d0.x, d0.y, d0.z, d0.w, d1.x, d1.y, d1.z, d1.w};

    int jstart = 960 * km - 480; if (jstart < 0) jstart = 0;
    int jend   = 960 * km + 480; if (jend > LW)  jend = LW;
    int ppbase = 481 - 960 * km;
    float* outn = out + (size_t)n * LW;

    for (int j = jstart + tid; j < jend; j += 256) {
        int ppi = j + ppbase;                       // pp = p+1 (head: j+481)
        double pp = (double)ppi;
        double tb = fma(pp, fma(Qv, pp, Sv), Pv);   // cycles
        double fr = tb - floor(tb);                 // frac in f64, once
        float f1 = (float)fr;
        float w  = ((float)ppi - 0.5f) * (1.0f / 960.0f);
        float acc = 0.0f;
        #pragma unroll
        for (int h = 0; h < NHH; h++) {
            float fh = f1 * (float)(h + 1);
            float sv;
            asm("v_fract_f32 %0, %1\n\tv_sin_f32 %0, %0" : "=v"(sv) : "v"(fh));
            acc = fmaf(fmaf(md[h], w, ma[h]), sv, acc);
        }
        outn[j] = acc * 0.125f;
    }
}

extern "C" void kernel_launch(void* const* d_in, const int* in_sizes, int n_in,
                              void* d_out, int out_size, void* d_ws, size_t ws_size,
                              hipStream_t stream) {
    const float* x        = (const float*)d_in[0];
    const float* mag_w    = (const float*)d_in[1];
    const float* mag_b    = (const float*)d_in[2];
    const float* cn_scale = (const float*)d_in[3];
    const float* cn_shift = (const float*)d_in[4];
    const float* oct_w    = (const float*)d_in[5];
    const float* oct_b    = (const float*)d_in[6];
    float* out = (float*)d_out;

    // ws: f0 f64[3200] | P,S,Q f64[16*201] | mag f32[16*8*200] | magA,magD f32[16*201*8]
    double* f0  = (double*)d_ws;
    double* P   = f0 + NB * LFR;
    double* S   = P + NB * NKM;
    double* Q   = S + NB * NKM;
    float*  mag  = (float*)(Q + NB * NKM);
    float*  magA = mag + NB * NHH * LFR;
    float*  magD = magA + NB * NKM * 8;

    hg_frames<<<dim3(NB * LFR), dim3(64), 0, stream>>>(
        x, mag_w, mag_b, cn_scale, cn_shift, oct_w, oct_b, f0, mag);
    hg_tables<<<dim3(NB), dim3(64), 0, stream>>>(f0, mag, P, S, Q, magA, magD);
    hg_wave<<<dim3(NKM, NB), dim3(256), 0, stream>>>(P, S, Q, magA, magD, out);
}

// Round 3
// 27.374 us; speedup vs baseline: 1.6915x; 1.3535x over previous
//
#include <hip/hip_runtime.h>
#include <math.h>

// HarmonicGenerator: closed-form piecewise-linear cumsum.
// K1 (hg_prep): per-n block computes frame stats (f64, per-lane serial),
//   prefix scan, and per-region f32 tables {frac(P'), S', Q, magA, magD}
//   with the phase polynomial recentered at the region midpoint.
// K2 (hg_wave): pure-f32 per-sample evaluation, HW v_fract/v_sin.
// N=16, C=256, LF=200, SEG=960, Lw=192000, NH=8, SR=48000.

#define NB   16
#define CCH  256
#define LFR  200
#define LW   192000
#define NHH  8
#define NKM  201
#define INV_SR (1.0 / 48000.0)
#define PSTRIDE 20   // floats per (n,km) param record

__device__ inline double wave_sum64(double v) {
    #pragma unroll
    for (int off = 32; off > 0; off >>= 1) v += __shfl_xor(v, off);
    return v;
}
__device__ inline double wave_incl_scan64(double v) {
    int lane = threadIdx.x & 63;
    #pragma unroll
    for (int off = 1; off < 64; off <<= 1) {
        double t = __shfl_up(v, off);
        if (lane >= off) v += t;
    }
    return v;
}

// K1: one block per n. 1024 threads = 4 channel-groups x 256 frame-slots.
__global__ __launch_bounds__(1024)
void hg_prep(const float* __restrict__ x,
             const float* __restrict__ mag_w, const float* __restrict__ mag_b,
             const float* __restrict__ cn_scale, const float* __restrict__ cn_shift,
             const float* __restrict__ oct_w, const float* __restrict__ oct_b,
             float* __restrict__ params) {
    __shared__ double w2l[CCH];                 // scale[c]*ow[c], f64
    __shared__ double psum[4][256], psumsq[4][256], pdotx[4][256];
    __shared__ float  pmag[NHH][4][256];
    __shared__ double redA[4], redB[4];
    __shared__ double SAB[2];
    __shared__ double Fl[LFR];
    __shared__ double Tl[LFR];
    __shared__ float  Mgl[LFR][NHH];

    int n   = blockIdx.x;
    int tid = threadIdx.x;
    int t   = tid & 255;        // frame slot
    int g   = tid >> 8;         // channel group 0..3
    int lane = tid & 63;
    int wv  = tid >> 6;

    // prologue: w2[c] = scale*ow (f64), SA = sum(scale*ow), SB = sum(shift*ow)
    double sa = 0.0, sb = 0.0;
    if (tid < CCH) {
        double sc = (double)cn_scale[tid];
        double sh = (double)cn_shift[tid];
        double ow = (double)oct_w[tid];
        double w2 = sc * ow;
        w2l[tid] = w2;
        sa = w2;
        sb = sh * ow;
    }
    sa = wave_sum64(sa);
    sb = wave_sum64(sb);
    if (tid < CCH && lane == 0) { redA[wv] = sa; redB[wv] = sb; }
    __syncthreads();
    if (tid == 0) {
        SAB[0] = redA[0] + redA[1] + redA[2] + redA[3];
        SAB[1] = redB[0] + redB[1] + redB[2] + redB[3];
    }

    // main accumulation: lane owns frame t, loops 64 channels of group g
    int gs = __builtin_amdgcn_readfirstlane(g);
    const float* xb = x + (size_t)n * CCH * LFR;
    double s = 0.0, s2 = 0.0, dx = 0.0;
    float zm[NHH] = {0.f, 0.f, 0.f, 0.f, 0.f, 0.f, 0.f, 0.f};
    #pragma unroll 4
    for (int cc = 0; cc < 64; cc++) {
        int c = gs * 64 + cc;
        float xf = (t < LFR) ? xb[c * LFR + t] : 0.f;
        double xd = (double)xf;
        s  += xd;
        s2  = fma(xd, xd, s2);
        dx  = fma(xd, w2l[c], dx);
        #pragma unroll
        for (int h = 0; h < NHH; h++)
            zm[h] = fmaf(xf, mag_w[h * CCH + c], zm[h]);
    }
    psum[g][t] = s; psumsq[g][t] = s2; pdotx[g][t] = dx;
    #pragma unroll
    for (int h = 0; h < NHH; h++) pmag[h][g][t] = zm[h];
    __syncthreads();

    // combine + per-frame stats
    if (tid < LFR) {
        double sum = psum[0][tid] + psum[1][tid] + psum[2][tid] + psum[3][tid];
        double ssq = psumsq[0][tid] + psumsq[1][tid] + psumsq[2][tid] + psumsq[3][tid];
        double dot = pdotx[0][tid] + pdotx[1][tid] + pdotx[2][tid] + pdotx[3][tid];
        double mu  = sum * (1.0 / 256.0);
        double var = (ssq - sum * mu) * (1.0 / 255.0);
        double inv = 1.0 / (sqrt(var) + 1e-4);            // unbiased std + EPS
        double oct = inv * (dot - mu * SAB[0]) + SAB[1] + (double)oct_b[0];
        double f0  = 440.0 * exp2(oct);
        f0 = fmin(fmax(f0, 20.0), 16000.0);
        Fl[tid] = f0;
        #pragma unroll
        for (int h = 0; h < NHH; h++) {
            float z = pmag[h][0][tid] + pmag[h][1][tid] + pmag[h][2][tid]
                    + pmag[h][3][tid] + mag_b[h];
            Mgl[tid][h] = expf(fminf(z, 6.f));
        }
    }
    __syncthreads();

    // exclusive scan of region sums by wave 0: Tl[k] = 480*F[0] + sum_{i<k} 480*(F[i]+F[i+1])
    if (tid < 64) {
        double carry = 480.0 * Fl[0];
        for (int base = 0; base < LFR; base += 64) {
            int k = base + tid;
            double d = (k < LFR - 1) ? 480.0 * (Fl[k] + Fl[k + 1]) : 0.0;
            double scn = wave_incl_scan64(d);
            if (k < LFR) Tl[k] = carry + scn - d;
            carry += __shfl(scn, 63);
        }
    }
    __syncthreads();

    // per-region tables, recentered: tb(pc) = P' + S'*pc + Q*pc^2, pc in [-479,480]
    // P' = P + 480*S + 230400*Q ; S' = S + 960*Q ; store frac(P') as f32.
    if (tid < NKM) {
        int km = tid;
        int kc = min(max(km - 1, 0), LFR - 1);
        bool body = (km >= 1 && km <= LFR - 1);
        double Sd = Fl[kc] * INV_SR;
        double Qd = body ? (Fl[km] - Fl[km - 1]) * (INV_SR / 1920.0) : 0.0;
        double Pd = (km == 0) ? (-480.0 * Fl[0] * INV_SR) : Tl[km - 1] * INV_SR;
        double Pp = Pd + 480.0 * Sd + 230400.0 * Qd;
        double Sp = Sd + 960.0 * Qd;
        float* pr = params + ((size_t)n * NKM + km) * PSTRIDE;
        pr[0] = (float)(Pp - floor(Pp));
        pr[1] = (float)Sp;
        pr[2] = (float)Qd;
        pr[3] = 0.f;
        #pragma unroll
        for (int h = 0; h < NHH; h++) {
            float a = Mgl[kc][h];
            pr[4 + h]  = a;
            pr[12 + h] = body ? (Mgl[km][h] - a) : 0.f;
        }
    }
}

// K2: one block per (region km, n); all params block-uniform; pure f32.
__global__ __launch_bounds__(256)
void hg_wave(const float* __restrict__ params, float* __restrict__ out) {
    int km = blockIdx.x, n = blockIdx.y;
    const float4* pb = (const float4*)(params + ((size_t)n * NKM + km) * PSTRIDE);
    float4 v0 = pb[0], v1 = pb[1], v2 = pb[2], v3 = pb[3], v4 = pb[4];
    float Pf = v0.x, Sf = v0.y, Qf = v0.z;
    float ma[NHH] = {v1.x, v1.y, v1.z, v1.w, v2.x, v2.y, v2.z, v2.w};
    float md[NHH] = {v3.x, v3.y, v3.z, v3.w, v4.x, v4.y, v4.z, v4.w};

    int jstart = 960 * km - 480; if (jstart < 0) jstart = 0;
    int jend   = 960 * km + 480; if (jend > LW)  jend = LW;
    int pcbase = 1 - 960 * km;
    float* outn = out + (size_t)n * LW;

    for (int j = jstart + (int)threadIdx.x; j < jend; j += 256) {
        float pc = (float)(j + pcbase);                 // in [-479, 480]
        float t1 = fmaf(Qf, pc, Sf);
        float tb = fmaf(pc, t1, Pf);                    // phase (cycles), |tb| <~ 200
        float fr;
        asm("v_fract_f32 %0, %1" : "=v"(fr) : "v"(tb));
        float w = (pc + 479.5f) * (1.0f / 960.0f);
        float acc = 0.f;
        #pragma unroll
        for (int h = 0; h < NHH; h++) {
            float fh = fr * (float)(h + 1);
            float sv;
            asm("v_fract_f32 %0, %1\n\tv_sin_f32 %0, %0" : "=v"(sv) : "v"(fh));
            acc = fmaf(fmaf(md[h], w, ma[h]), sv, acc);
        }
        outn[j] = acc * 0.125f;
    }
}

extern "C" void kernel_launch(void* const* d_in, const int* in_sizes, int n_in,
                              void* d_out, int out_size, void* d_ws, size_t ws_size,
                              hipStream_t stream) {
    const float* x        = (const float*)d_in[0];
    const float* mag_w    = (const float*)d_in[1];
    const float* mag_b    = (const float*)d_in[2];
    const float* cn_scale = (const float*)d_in[3];
    const float* cn_shift = (const float*)d_in[4];
    const float* oct_w    = (const float*)d_in[5];
    const float* oct_b    = (const float*)d_in[6];
    float* out = (float*)d_out;

    float* params = (float*)d_ws;   // 16*201*20 floats = 257 KB

    hg_prep<<<dim3(NB), dim3(1024), 0, stream>>>(
        x, mag_w, mag_b, cn_scale, cn_shift, oct_w, oct_b, params);
    hg_wave<<<dim3(NKM, NB), dim3(256), 0, stream>>>(params, out);
}

// Round 4
// 23.056 us; speedup vs baseline: 2.0082x; 1.1872x over previous
//
#include <hip/hip_runtime.h>
#include <math.h>

// HarmonicGenerator: closed-form piecewise-linear cumsum.
// K1a hg_partial: (NB x CG) blocks accumulate per-frame partial sums over
//   32 channels each (coalesced; f64 for the norm/octave chains).
// K1b hg_tables: per-n block combines partials, frame stats -> f0 (f64),
//   prefix scan, per-region f32 tables {frac(P'), S', Q, magA, magD}
//   (phase polynomial recentered at region midpoint).
// K2 hg_wave: pure-f32, one float4 store per thread, HW v_fract/v_sin
//   (v_sin input is revolutions).
// N=16, C=256, LF=200, SEG=960, Lw=192000, NH=8, SR=48000.

#define NB   16
#define CCH  256
#define LFR  200
#define LW   192000
#define NHH  8
#define NKM  201
#define CG   8       // channel groups (blocks) per n
#define CPB  32      // channels per group
#define INV_SR (1.0 / 48000.0)
#define PSTRIDE 20   // floats per (n,km) param record

__device__ inline double wave_sum64(double v) {
    #pragma unroll
    for (int off = 32; off > 0; off >>= 1) v += __shfl_xor(v, off);
    return v;
}
__device__ inline double wave_incl_scan64(double v) {
    int lane = threadIdx.x & 63;
    #pragma unroll
    for (int off = 1; off < 64; off <<= 1) {
        double t = __shfl_up(v, off);
        if (lane >= off) v += t;
    }
    return v;
}

// K1a: partial sums. Thread = frame slot t; loops CPB channels (uniform c ->
// scalar weight loads, coalesced x loads across t).
__global__ __launch_bounds__(256)
void hg_partial(const float* __restrict__ x,
                const float* __restrict__ mag_w,
                const float* __restrict__ cn_scale,
                const float* __restrict__ oct_w,
                double* __restrict__ ps, double* __restrict__ ps2,
                double* __restrict__ pdx, float* __restrict__ pmg) {
    int n = blockIdx.x, cg = blockIdx.y;
    int t = threadIdx.x;
    const float* xb = x + (size_t)n * CCH * LFR;
    int cbase = cg * CPB;

    double s = 0.0, s2 = 0.0, dx = 0.0;
    float zm[NHH] = {0.f, 0.f, 0.f, 0.f, 0.f, 0.f, 0.f, 0.f};
    #pragma unroll 8
    for (int cc = 0; cc < CPB; cc++) {
        int c = cbase + cc;
        float xf = (t < LFR) ? xb[(size_t)c * LFR + t] : 0.f;
        double xd = (double)xf;
        double w2 = (double)cn_scale[c] * (double)oct_w[c];
        s += xd;
        s2 = fma(xd, xd, s2);
        dx = fma(xd, w2, dx);
        #pragma unroll
        for (int h = 0; h < NHH; h++)
            zm[h] = fmaf(xf, mag_w[h * CCH + c], zm[h]);
    }
    size_t pi = ((size_t)n * CG + cg) * 256 + t;
    ps[pi] = s; ps2[pi] = s2; pdx[pi] = dx;
    #pragma unroll
    for (int h = 0; h < NHH; h++)
        pmg[(((size_t)n * CG + cg) * NHH + h) * 256 + t] = zm[h];
}

// K1b: per-n combine + stats + scan + tables.
__global__ __launch_bounds__(256)
void hg_tables(const double* __restrict__ ps, const double* __restrict__ ps2,
               const double* __restrict__ pdx, const float* __restrict__ pmg,
               const float* __restrict__ mag_b,
               const float* __restrict__ cn_scale, const float* __restrict__ cn_shift,
               const float* __restrict__ oct_w, const float* __restrict__ oct_b,
               float* __restrict__ params) {
    __shared__ double Fl[LFR];
    __shared__ double Tl[LFR];
    __shared__ float  Mgl[LFR][NHH];
    __shared__ double SAB[2];

    int n = blockIdx.x, tid = threadIdx.x;

    // SA = sum(scale*ow), SB = sum(shift*ow)  (wave 0, f64)
    if (tid < 64) {
        double sa = 0.0, sb = 0.0;
        #pragma unroll
        for (int k = 0; k < 4; k++) {
            int c = tid + 64 * k;
            double ow = (double)oct_w[c];
            sa = fma((double)cn_scale[c], ow, sa);
            sb = fma((double)cn_shift[c], ow, sb);
        }
        sa = wave_sum64(sa);
        sb = wave_sum64(sb);
        if (tid == 0) { SAB[0] = sa; SAB[1] = sb; }
    }
    __syncthreads();

    if (tid < LFR) {
        double s = 0.0, s2 = 0.0, dx = 0.0;
        #pragma unroll
        for (int cg = 0; cg < CG; cg++) {
            size_t pi = ((size_t)n * CG + cg) * 256 + tid;
            s += ps[pi]; s2 += ps2[pi]; dx += pdx[pi];
        }
        double mu  = s * (1.0 / 256.0);
        double var = (s2 - s * mu) * (1.0 / 255.0);
        double inv = 1.0 / (sqrt(var) + 1e-4);          // unbiased std + EPS
        double oct = inv * (dx - mu * SAB[0]) + SAB[1] + (double)oct_b[0];
        double f0  = 440.0 * exp2(oct);
        Fl[tid] = fmin(fmax(f0, 20.0), 16000.0);
        #pragma unroll
        for (int h = 0; h < NHH; h++) {
            float z = 0.f;
            #pragma unroll
            for (int cg = 0; cg < CG; cg++)
                z += pmg[(((size_t)n * CG + cg) * NHH + h) * 256 + tid];
            Mgl[tid][h] = expf(fminf(z + mag_b[h], 6.f));
        }
    }
    __syncthreads();

    // exclusive scan: Tl[k] = 480*F[0] + sum_{i<k} 480*(F[i]+F[i+1])
    if (tid < 64) {
        double carry = 480.0 * Fl[0];
        for (int base = 0; base < LFR; base += 64) {
            int k = base + tid;
            double d = (k < LFR - 1) ? 480.0 * (Fl[k] + Fl[k + 1]) : 0.0;
            double scn = wave_incl_scan64(d);
            if (k < LFR) Tl[k] = carry + scn - d;
            carry += __shfl(scn, 63);
        }
    }
    __syncthreads();

    // tables, recentered: tb(pc) = P' + S'*pc + Q*pc^2, pc in [-479,480]
    if (tid < NKM) {
        int km = tid;
        int kc = min(max(km - 1, 0), LFR - 1);
        bool body = (km >= 1 && km <= LFR - 1);
        double Sd = Fl[kc] * INV_SR;
        double Qd = body ? (Fl[km] - Fl[km - 1]) * (INV_SR / 1920.0) : 0.0;
        double Pd = (km == 0) ? (-480.0 * Fl[0] * INV_SR) : Tl[km - 1] * INV_SR;
        double Pp = Pd + 480.0 * Sd + 230400.0 * Qd;
        double Sp = Sd + 960.0 * Qd;
        float* pr = params + ((size_t)n * NKM + km) * PSTRIDE;
        pr[0] = (float)(Pp - floor(Pp));
        pr[1] = (float)Sp;
        pr[2] = (float)Qd;
        pr[3] = 0.f;
        #pragma unroll
        for (int h = 0; h < NHH; h++) {
            float a = Mgl[kc][h];
            pr[4 + h]  = a;
            pr[12 + h] = body ? (Mgl[km][h] - a) : 0.f;
        }
    }
}

// K2: block per (region km, n); 4 consecutive samples/thread, float4 store.
// pc = 4*tid - 479 + u, region-independent.
__global__ __launch_bounds__(256)
void hg_wave(const float* __restrict__ params, float* __restrict__ out) {
    int km = blockIdx.x, n = blockIdx.y;
    const float4* pb = (const float4*)(params + ((size_t)n * NKM + km) * PSTRIDE);
    float4 v0 = pb[0], v1 = pb[1], v2 = pb[2], v3 = pb[3], v4 = pb[4];
    float Pf = v0.x, Sf = v0.y, Qf = v0.z;
    float ma[NHH] = {v1.x, v1.y, v1.z, v1.w, v2.x, v2.y, v2.z, v2.w};
    float md[NHH] = {v3.x, v3.y, v3.z, v3.w, v4.x, v4.y, v4.z, v4.w};

    int tid = threadIdx.x;
    if (tid >= 240) return;
    int j0 = 960 * km - 480 + tid * 4;
    if (j0 < 0 || j0 >= LW) return;       // clipped head/tail threads

    float r[4];
    #pragma unroll
    for (int u = 0; u < 4; u++) {
        float pc = (float)(tid * 4 - 479 + u);          // [-479, 480]
        float tb = fmaf(pc, fmaf(Qf, pc, Sf), Pf);      // phase (cycles)
        float fr;
        asm("v_fract_f32 %0, %1" : "=v"(fr) : "v"(tb));
        float w = (pc + 479.5f) * (1.0f / 960.0f);
        float acc = 0.f;
        #pragma unroll
        for (int h = 0; h < NHH; h++) {
            float fh = fr * (float)(h + 1);
            float sv;
            asm("v_fract_f32 %0, %1\n\tv_sin_f32 %0, %0" : "=v"(sv) : "v"(fh));
            acc = fmaf(fmaf(md[h], w, ma[h]), sv, acc);
        }
        r[u] = acc * 0.125f;
    }
    *(float4*)(out + (size_t)n * LW + j0) = make_float4(r[0], r[1], r[2], r[3]);
}

extern "C" void kernel_launch(void* const* d_in, const int* in_sizes, int n_in,
                              void* d_out, int out_size, void* d_ws, size_t ws_size,
                              hipStream_t stream) {
    const float* x        = (const float*)d_in[0];
    const float* mag_w    = (const float*)d_in[1];
    const float* mag_b    = (const float*)d_in[2];
    const float* cn_scale = (const float*)d_in[3];
    const float* cn_shift = (const float*)d_in[4];
    const float* oct_w    = (const float*)d_in[5];
    const float* oct_b    = (const float*)d_in[6];
    float* out = (float*)d_out;

    // ws: ps|ps2|pdx f64[NB*CG*256] each, pmg f32[NB*CG*8*256], params f32
    double* ps  = (double*)d_ws;
    double* ps2 = ps  + (size_t)NB * CG * 256;
    double* pdx = ps2 + (size_t)NB * CG * 256;
    float*  pmg = (float*)(pdx + (size_t)NB * CG * 256);
    float*  params = pmg + (size_t)NB * CG * NHH * 256;

    hg_partial<<<dim3(NB, CG), dim3(256), 0, stream>>>(
        x, mag_w, cn_scale, oct_w, ps, ps2, pdx, pmg);
    hg_tables<<<dim3(NB), dim3(256), 0, stream>>>(
        ps, ps2, pdx, pmg, mag_b, cn_scale, cn_shift, oct_w, oct_b, params);
    hg_wave<<<dim3(NKM, NB), dim3(256), 0, stream>>>(params, out);
}

// Round 5
// 22.792 us; speedup vs baseline: 2.0315x; 1.0116x over previous
//
#include <hip/hip_runtime.h>
#include <math.h>

// HarmonicGenerator: closed-form piecewise-linear cumsum.
// K1a hg_partial: (NB x CG) blocks accumulate per-frame partial sums over
//   32 channels each (coalesced; f64 for the norm/octave chains).
// K1b hg_tables: per-n block combines partials, frame stats -> f0 (f64),
//   prefix scan, per-region f32 tables {frac(P'), S', Q, magA, magD}
//   (phase polynomial recentered at region midpoint).
// K2 hg_wave: pure-f32; 4 tiles per block; per sample ONE fract+sin+cos,
//   harmonics 2..8 via Chebyshev recurrence s_{h+1}=2c*s_h - s_{h-1}.
// N=16, C=256, LF=200, SEG=960, Lw=192000, NH=8, SR=48000.

#define NB   16
#define CCH  256
#define LFR  200
#define LW   192000
#define NHH  8
#define NKM  201
#define CG   8       // channel groups (blocks) per n
#define CPB  32      // channels per group
#define INV_SR (1.0 / 48000.0)
#define PSTRIDE 20   // floats per (n,km) param record
#define TPB  4       // tiles per wave-kernel block

__device__ inline double wave_sum64(double v) {
    #pragma unroll
    for (int off = 32; off > 0; off >>= 1) v += __shfl_xor(v, off);
    return v;
}
__device__ inline double wave_incl_scan64(double v) {
    int lane = threadIdx.x & 63;
    #pragma unroll
    for (int off = 1; off < 64; off <<= 1) {
        double t = __shfl_up(v, off);
        if (lane >= off) v += t;
    }
    return v;
}

// K1a: partial sums. Thread = frame slot t; loops CPB channels (uniform c ->
// scalar weight loads, coalesced x loads across t).
__global__ __launch_bounds__(256)
void hg_partial(const float* __restrict__ x,
                const float* __restrict__ mag_w,
                const float* __restrict__ cn_scale,
                const float* __restrict__ oct_w,
                double* __restrict__ ps, double* __restrict__ ps2,
                double* __restrict__ pdx, float* __restrict__ pmg) {
    int n = blockIdx.x, cg = blockIdx.y;
    int t = threadIdx.x;
    const float* xb = x + (size_t)n * CCH * LFR;
    int cbase = cg * CPB;

    double s = 0.0, s2 = 0.0, dx = 0.0;
    float zm[NHH] = {0.f, 0.f, 0.f, 0.f, 0.f, 0.f, 0.f, 0.f};
    #pragma unroll 8
    for (int cc = 0; cc < CPB; cc++) {
        int c = cbase + cc;
        float xf = (t < LFR) ? xb[(size_t)c * LFR + t] : 0.f;
        double xd = (double)xf;
        double w2 = (double)cn_scale[c] * (double)oct_w[c];
        s += xd;
        s2 = fma(xd, xd, s2);
        dx = fma(xd, w2, dx);
        #pragma unroll
        for (int h = 0; h < NHH; h++)
            zm[h] = fmaf(xf, mag_w[h * CCH + c], zm[h]);
    }
    size_t pi = ((size_t)n * CG + cg) * 256 + t;
    ps[pi] = s; ps2[pi] = s2; pdx[pi] = dx;
    #pragma unroll
    for (int h = 0; h < NHH; h++)
        pmg[(((size_t)n * CG + cg) * NHH + h) * 256 + t] = zm[h];
}

// K1b: per-n combine + stats + scan + tables.
__global__ __launch_bounds__(256)
void hg_tables(const double* __restrict__ ps, const double* __restrict__ ps2,
               const double* __restrict__ pdx, const float* __restrict__ pmg,
               const float* __restrict__ mag_b,
               const float* __restrict__ cn_scale, const float* __restrict__ cn_shift,
               const float* __restrict__ oct_w, const float* __restrict__ oct_b,
               float* __restrict__ params) {
    __shared__ double Fl[LFR];
    __shared__ double Tl[LFR];
    __shared__ float  Mgl[LFR][NHH];
    __shared__ double SAB[2];

    int n = blockIdx.x, tid = threadIdx.x;

    // SA = sum(scale*ow), SB = sum(shift*ow)  (wave 0, f64)
    if (tid < 64) {
        double sa = 0.0, sb = 0.0;
        #pragma unroll
        for (int k = 0; k < 4; k++) {
            int c = tid + 64 * k;
            double ow = (double)oct_w[c];
            sa = fma((double)cn_scale[c], ow, sa);
            sb = fma((double)cn_shift[c], ow, sb);
        }
        sa = wave_sum64(sa);
        sb = wave_sum64(sb);
        if (tid == 0) { SAB[0] = sa; SAB[1] = sb; }
    }
    __syncthreads();

    if (tid < LFR) {
        double s = 0.0, s2 = 0.0, dx = 0.0;
        #pragma unroll
        for (int cg = 0; cg < CG; cg++) {
            size_t pi = ((size_t)n * CG + cg) * 256 + tid;
            s += ps[pi]; s2 += ps2[pi]; dx += pdx[pi];
        }
        double mu  = s * (1.0 / 256.0);
        double var = (s2 - s * mu) * (1.0 / 255.0);
        double inv = 1.0 / (sqrt(var) + 1e-4);          // unbiased std + EPS
        double oct = inv * (dx - mu * SAB[0]) + SAB[1] + (double)oct_b[0];
        double f0  = 440.0 * exp2(oct);
        Fl[tid] = fmin(fmax(f0, 20.0), 16000.0);
        #pragma unroll
        for (int h = 0; h < NHH; h++) {
            float z = 0.f;
            #pragma unroll
            for (int cg = 0; cg < CG; cg++)
                z += pmg[(((size_t)n * CG + cg) * NHH + h) * 256 + tid];
            Mgl[tid][h] = expf(fminf(z + mag_b[h], 6.f));
        }
    }
    __syncthreads();

    // exclusive scan: Tl[k] = 480*F[0] + sum_{i<k} 480*(F[i]+F[i+1])
    if (tid < 64) {
        double carry = 480.0 * Fl[0];
        for (int base = 0; base < LFR; base += 64) {
            int k = base + tid;
            double d = (k < LFR - 1) ? 480.0 * (Fl[k] + Fl[k + 1]) : 0.0;
            double scn = wave_incl_scan64(d);
            if (k < LFR) Tl[k] = carry + scn - d;
            carry += __shfl(scn, 63);
        }
    }
    __syncthreads();

    // tables, recentered: tb(pc) = P' + S'*pc + Q*pc^2, pc in [-479,480]
    if (tid < NKM) {
        int km = tid;
        int kc = min(max(km - 1, 0), LFR - 1);
        bool body = (km >= 1 && km <= LFR - 1);
        double Sd = Fl[kc] * INV_SR;
        double Qd = body ? (Fl[km] - Fl[km - 1]) * (INV_SR / 1920.0) : 0.0;
        double Pd = (km == 0) ? (-480.0 * Fl[0] * INV_SR) : Tl[km - 1] * INV_SR;
        double Pp = Pd + 480.0 * Sd + 230400.0 * Qd;
        double Sp = Sd + 960.0 * Qd;
        float* pr = params + ((size_t)n * NKM + km) * PSTRIDE;
        pr[0] = (float)(Pp - floor(Pp));
        pr[1] = (float)Sp;
        pr[2] = (float)Qd;
        pr[3] = 0.f;
        #pragma unroll
        for (int h = 0; h < NHH; h++) {
            float a = Mgl[kc][h];
            pr[4 + h]  = a;
            pr[12 + h] = body ? (Mgl[km][h] - a) : 0.f;
        }
    }
}

// K2: 4 tiles (km,n) per block; 4 consecutive samples/thread per tile.
// Chebyshev: s_{h+1} = 2*cos(2*pi*f)*s_h - s_{h-1}.
__global__ __launch_bounds__(256)
void hg_wave(const float* __restrict__ params, float* __restrict__ out) {
    int tid = threadIdx.x;
    #pragma unroll
    for (int i = 0; i < TPB; i++) {
        int tile = blockIdx.x * TPB + i;               // 0..3215
        int n = tile / NKM, km = tile - n * NKM;
        const float4* pb = (const float4*)(params + (size_t)tile * PSTRIDE);
        float4 v0 = pb[0], v1 = pb[1], v2 = pb[2], v3 = pb[3], v4 = pb[4];
        float Pf = v0.x, Sf = v0.y, Qf = v0.z;
        float ma[NHH] = {v1.x, v1.y, v1.z, v1.w, v2.x, v2.y, v2.z, v2.w};
        float md[NHH] = {v3.x, v3.y, v3.z, v3.w, v4.x, v4.y, v4.z, v4.w};

        if (tid >= 240) continue;
        int j0 = 960 * km - 480 + tid * 4;
        if (j0 < 0 || j0 >= LW) continue;              // clipped head/tail

        float r[4];
        #pragma unroll
        for (int u = 0; u < 4; u++) {
            float pc = (float)(tid * 4 - 479 + u);     // [-479, 480]
            float tb = fmaf(pc, fmaf(Qf, pc, Sf), Pf); // phase (cycles)
            float fr, s1, c1;
            asm("v_fract_f32 %0, %1" : "=v"(fr) : "v"(tb));
            asm("v_sin_f32 %0, %1" : "=v"(s1) : "v"(fr));
            asm("v_cos_f32 %0, %1" : "=v"(c1) : "v"(fr));
            float twoc = c1 + c1;
            float w = (pc + 479.5f) * (1.0f / 960.0f);
            float sp = 0.f, sc = s1;                   // s_0, s_1
            float acc = 0.f;
            #pragma unroll
            for (int h = 0; h < NHH; h++) {
                acc = fmaf(fmaf(md[h], w, ma[h]), sc, acc);
                float sn = fmaf(twoc, sc, -sp);
                sp = sc; sc = sn;
            }
            r[u] = acc * 0.125f;
        }
        *(float4*)(out + (size_t)n * LW + j0) = make_float4(r[0], r[1], r[2], r[3]);
    }
}

extern "C" void kernel_launch(void* const* d_in, const int* in_sizes, int n_in,
                              void* d_out, int out_size, void* d_ws, size_t ws_size,
                              hipStream_t stream) {
    const float* x        = (const float*)d_in[0];
    const float* mag_w    = (const float*)d_in[1];
    const float* mag_b    = (const float*)d_in[2];
    const float* cn_scale = (const float*)d_in[3];
    const float* cn_shift = (const float*)d_in[4];
    const float* oct_w    = (const float*)d_in[5];
    const float* oct_b    = (const float*)d_in[6];
    float* out = (float*)d_out;

    // ws: ps|ps2|pdx f64[NB*CG*256] each, pmg f32[NB*CG*8*256], params f32
    double* ps  = (double*)d_ws;
    double* ps2 = ps  + (size_t)NB * CG * 256;
    double* pdx = ps2 + (size_t)NB * CG * 256;
    float*  pmg = (float*)(pdx + (size_t)NB * CG * 256);
    float*  params = pmg + (size_t)NB * CG * NHH * 256;

    hg_partial<<<dim3(NB, CG), dim3(256), 0, stream>>>(
        x, mag_w, cn_scale, oct_w, ps, ps2, pdx, pmg);
    hg_tables<<<dim3(NB), dim3(256), 0, stream>>>(
        ps, ps2, pdx, pmg, mag_b, cn_scale, cn_shift, oct_w, oct_b, params);
    hg_wave<<<dim3((NKM * NB) / TPB), dim3(256), 0, stream>>>(params, out);
}